// Round 2
// baseline (178.810 us; speedup 1.0000x reference)
//
#include <hip/hip_runtime.h>
#include <hip/hip_bf16.h>
#include <math.h>

#define NN 2048
#define BB 32
#define NT 64                 // total K-dim MFMA iterations: 2048 / 32
#define NBLK 256              // block = (osc_tile 0..127, batch_half 0..1)
#define DT_C 0.1f
#define PI_F 3.14159265358979323846f
#define TWO_PI_F 6.28318530717958647692f
#define MAGIC 0x5EED5EEDu

// ws layout (sync words line-padded):
//   READY @ 256, CNT[4] @ 512 + 256*idx  (idx = bh*2 + khalf)
//   ACC @ 80 KB: sin[32], cos[32] fp32 sums + arrival counter (atomic tail)
//   tables @ 128 KB: 10 per-step packed tables, reverse order, 1 MB apart
#define READY_OFF  256
#define CNT_OFF    512
#define CNT_STRIDE 256
#define ACC_OFF    81920
#define TAB_BASE   131072
#define TAB_STRIDE (1u << 20)

typedef __attribute__((ext_vector_type(8))) short short8;
typedef __attribute__((ext_vector_type(4))) float floatx4;

__device__ __forceinline__ unsigned short f2bf(float x) {
    union { float f; unsigned int u; } v; v.f = x;
    unsigned int r = v.u + 0x7FFFu + ((v.u >> 16) & 1u);
    return (unsigned short)(r >> 16);
}

// sc1 write-through store / L2-bypass load (agent-coherent, no cache walks)
__device__ __forceinline__ void st_sc(unsigned int* p, unsigned int v) {
    __hip_atomic_store(p, v, __ATOMIC_RELAXED, __HIP_MEMORY_SCOPE_AGENT);
}
__device__ __forceinline__ unsigned int ld_sc(const unsigned int* p) {
    return __hip_atomic_load((unsigned int*)p, __ATOMIC_RELAXED,
                             __HIP_MEMORY_SCOPE_AGENT);
}
__device__ __forceinline__ void add_sc(unsigned int* p, unsigned int v) {
    __hip_atomic_fetch_add(p, v, __ATOMIC_RELAXED, __HIP_MEMORY_SCOPE_AGENT);
}

// ROUND-12 sync: NO grid barrier. Per-(batch-half, K-half) monotonic counter.
// Producer: table stores -> s_waitcnt(0) drain -> one atomic +1.
// Consumer wave: polls ONE word (all lanes same addr = 1 coalesced request)
// until 64*(step+1). Critical path = drain + last add + 1 poll RT, vs the
// old aggregator's drain + flag RT + gather RT + epoch RT + poll RT.
// Tables are write-once per step (10 disjoint buffers) -> no WAR hazard,
// so dropping the full barrier is safe.
__device__ __forceinline__ void wait_cnt(const unsigned int* c, unsigned int tgt) {
    while (ld_sc(c) < tgt)
        __builtin_amdgcn_s_sleep(2);
    // pin: no table loads may be scheduled above the poll exit
    __builtin_amdgcn_sched_barrier(0);
}

// unpack packed word pair {(s<<16)|c} x2 -> packed bf16x2 sin and cos
__device__ __forceinline__ void unpack2(unsigned int lo, unsigned int hi,
                                        unsigned int& sp, unsigned int& cp) {
    sp = __builtin_amdgcn_perm(hi, lo, 0x07060302u);  // {s1,s0}
    cp = __builtin_amdgcn_perm(hi, lo, 0x05040100u);  // {c1,c0}
}

// ROUND-12: dataflow-counter sync (see wait_cnt). Compute loop, prologue and
// math identical to round 11 for clean attribution. red[] double-buffered by
// step parity -> one __syncthreads per step (barrier pairing makes the WAR on
// red[s&1] safe: wave1 rewrites it only after passing barrier s+1, which
// requires wave0 to have read it after barrier s).
// Fragment layout (m89/m91-verified): A: lane holds A[m=lane&15][k=(lane>>4)*8+j];
// B mirrored; D: row(batch)=(lane>>4)*4+r, col(osc)=lane&15.
__global__ void __launch_bounds__(128, 1) kuramoto_fused(
    const float* __restrict__ theta0, const float* __restrict__ K,
    const float* __restrict__ omega, const float* __restrict__ K_global,
    const float* __restrict__ mu_gate,
    float* __restrict__ theta_out, float* __restrict__ coh,
    char* __restrict__ wsb)
{
    const int tid  = threadIdx.x;
    const int kh   = tid >> 6;              // K-half this wave covers: 0 or 1
    const int lane = tid & 63;
    const int lrow = lane & 15;
    const int kq   = lane >> 4;             // 0..3
    const int tile = blockIdx.x >> 1;
    const int bh   = blockIdx.x & 1;        // batch half
    const int i0   = tile * 16;
    const int b0   = bh * 16;
    const int i    = i0 + lrow;
    const int myhalf = tile >> 6;           // K-half this block PRODUCES into

    unsigned int* cntp = (unsigned int*)(wsb + CNT_OFF +
                                         (size_t)(bh * 2 + myhalf) * CNT_STRIDE);
    const unsigned int* cntc = (const unsigned int*)(wsb + CNT_OFF +
                                         (size_t)(bh * 2 + kh) * CNT_STRIDE);

    // one-time: drop pre-kernel (poison) lines from local caches before any
    // cached table read (belt-and-braces alongside launch acquire)
    __builtin_amdgcn_fence(__ATOMIC_ACQUIRE, "agent");

    // block 0 zeroes the (poisoned) counters + atomic-tail accumulators
    // before the ready handshake
    if (blockIdx.x == 0) {
        if (tid < 4)
            st_sc((unsigned int*)(wsb + CNT_OFF + (size_t)tid * CNT_STRIDE), 0u);
        if (tid < 66)                       // sin[32] cos[32] cnt (+pad)
            st_sc((unsigned int*)(wsb + ACC_OFF) + tid, 0u);
    }

    // per-step table s lives at wsb + TAB_BASE + (10-s)*TAB_STRIDE
    #define TAB(s) ((unsigned int*)(wsb + TAB_BASE + (size_t)(10 - (s)) * TAB_STRIDE))

    const float coef = K_global[0] * (DT_C / (float)NN);    // DT folded in

    // wave 0 owns theta for this block's 16x16 tile; TAB(0) issued FIRST so
    // its stores drain underneath the K staging loads
    float th[4], sb[4], cbv[4], om_dt = 0.f;
    if (kh == 0) {
        om_dt = omega[i] * DT_C;
        #pragma unroll
        for (int r = 0; r < 4; ++r) {
            size_t off = (size_t)(b0 + kq * 4 + r) * NN + i;
            th[r] = theta0[off];
            __sincosf(th[r], &sb[r], &cbv[r]);
            st_sc(&TAB(0)[off], ((unsigned int)f2bf(sb[r]) << 16) | f2bf(cbv[r]));
        }
    }

    // ---- K rows i0..i0+15 -> LDS as pre-scaled bf16 B-fragments ----
    // Batched loads: 16 float4 in flight per thread before converting.
    __shared__ short8 kb[NT * 64];          // 64 KB, kb[t*64 + lane]
    __shared__ floatx4 red[2][2][64];       // step-parity double-buffered P/Q
    const float kscale = mu_gate[0] * 0.5f; // MU_BRANCH_SCALE fold
    for (int g = 0; g < 4; ++g) {
        const int tb = kh * 32 + g * 8;
        float4 buf[16];
        #pragma unroll
        for (int j = 0; j < 8; ++j) {
            const float4* kp = (const float4*)(K + (size_t)i * NN + (tb + j) * 32 + kq * 8);
            buf[2 * j]     = kp[0];
            buf[2 * j + 1] = kp[1];
        }
        #pragma unroll
        for (int j = 0; j < 8; ++j) {
            float4 x = buf[2 * j], y = buf[2 * j + 1];
            short8 f;
            f[0] = (short)f2bf(x.x * kscale); f[1] = (short)f2bf(x.y * kscale);
            f[2] = (short)f2bf(x.z * kscale); f[3] = (short)f2bf(x.w * kscale);
            f[4] = (short)f2bf(y.x * kscale); f[5] = (short)f2bf(y.y * kscale);
            f[6] = (short)f2bf(y.z * kscale); f[7] = (short)f2bf(y.w * kscale);
            kb[(tb + j) * 64 + lane] = f;
        }
    }

    // drain zeros (block 0) + TAB(0) stores + staging; then ready handshake.
    // Handshake guarantees: counter zeros are at L3 before ANY block's first
    // atomic add (poison-clobber ordering).
    __syncthreads();
    if (tid == 0) {
        unsigned int* ready = (unsigned int*)(wsb + READY_OFF);
        if (blockIdx.x == 0) {
            st_sc(ready, MAGIC);            // zeros at L3 (vmcnt drained)
        } else {
            while (ld_sc(ready) != MAGIC)
                __builtin_amdgcn_s_sleep(8);
        }
    }
    __syncthreads();
    if (kh == 0 && lane == 0)
        add_sc(cntp, 1u);                   // TAB(0) tile published

    const int c0 = (blockIdx.x * 5) & 15;   // per-block K-loop rotation

    for (int step = 0; step < 10; ++step) {
        wait_cnt(cntc, 64u * (unsigned)(step + 1));
        const uint4* U = (const uint4*)(TAB(step) + (size_t)(b0 + lrow) * NN);
        unsigned int* tabn = TAB(step + 1);

        floatx4 p0 = {0.f,0.f,0.f,0.f}, p1 = {0.f,0.f,0.f,0.f};
        floatx4 q0 = {0.f,0.f,0.f,0.f}, q1 = {0.f,0.f,0.f,0.f};
        #pragma unroll 4
        for (int c = 0; c < 16; ++c) {      // this wave's K-half: 16 x 2 chunks
            const int t  = kh * 32 + 2 * ((c + c0) & 15);
            const int a0 = 8 * t + 2 * kq;  // uint4 idx: words j0..j0+7
            uint4 ua = U[a0];
            uint4 ub = U[a0 + 1];
            uint4 va = U[a0 + 8];           // chunk t+1
            uint4 vb = U[a0 + 9];
            union { short8 v; unsigned int u[4]; } as0, ac0, as1, ac1;
            unpack2(ua.x, ua.y, as0.u[0], ac0.u[0]);
            unpack2(ua.z, ua.w, as0.u[1], ac0.u[1]);
            unpack2(ub.x, ub.y, as0.u[2], ac0.u[2]);
            unpack2(ub.z, ub.w, as0.u[3], ac0.u[3]);
            unpack2(va.x, va.y, as1.u[0], ac1.u[0]);
            unpack2(va.z, va.w, as1.u[1], ac1.u[1]);
            unpack2(vb.x, vb.y, as1.u[2], ac1.u[2]);
            unpack2(vb.z, vb.w, as1.u[3], ac1.u[3]);
            short8 bk0 = kb[t * 64 + lane];
            short8 bk1 = kb[(t + 1) * 64 + lane];
            p0 = __builtin_amdgcn_mfma_f32_16x16x32_bf16(as0.v, bk0, p0, 0, 0, 0);
            q0 = __builtin_amdgcn_mfma_f32_16x16x32_bf16(ac0.v, bk0, q0, 0, 0, 0);
            p1 = __builtin_amdgcn_mfma_f32_16x16x32_bf16(as1.v, bk1, p1, 0, 0, 0);
            q1 = __builtin_amdgcn_mfma_f32_16x16x32_bf16(ac1.v, bk1, q1, 0, 0, 0);
        }
        floatx4 P = p0 + p1;
        floatx4 Q = q0 + q1;

        // K-split reduction: wave 1 publishes partials, wave 0 combines
        if (kh == 1) { red[step & 1][0][lane] = P; red[step & 1][1][lane] = Q; }
        __syncthreads();
        if (kh == 0) {
            P += red[step & 1][0][lane];
            Q += red[step & 1][1][lane];
            #pragma unroll
            for (int r = 0; r < 4; ++r) {
                float coup = cbv[r] * P[r] - sb[r] * Q[r];
                float tn = th[r] + om_dt + coef * coup;
                if (tn > PI_F)        tn -= TWO_PI_F;   // wrap to (-pi, pi]
                else if (tn <= -PI_F) tn += TWO_PI_F;
                th[r] = tn;
                __sincosf(tn, &sb[r], &cbv[r]);
                size_t off = (size_t)(b0 + kq * 4 + r) * NN + i;
                if (step < 9) {
                    st_sc(&tabn[off], ((unsigned int)f2bf(sb[r]) << 16) | f2bf(cbv[r]));
                } else {
                    theta_out[off] = tn;    // visible at kernel end
                }
            }
            if (step < 9) {
                __builtin_amdgcn_s_waitcnt(0);      // table stores at L3
                if (lane == 0) add_sc(cntp, 1u);    // publish tile for step+1
            }
        }
    }

    // ---- atomic coherence tail ----
    // wave 0 holds fp32 sin/cos of the final theta for rows b0+4*kq+r,
    // osc column i0+lrow. Reduce over the 16 osc lanes of each kq group,
    // publish via one 32-lane device-scope f32 atomic, count arrivals.
    if (kh == 0) {
        #pragma unroll
        for (int m = 1; m < 16; m <<= 1) {
            #pragma unroll
            for (int r = 0; r < 4; ++r) {
                sb[r]  += __shfl_xor(sb[r],  m, 64);
                cbv[r] += __shfl_xor(cbv[r], m, 64);
            }
        }
        float* sacc = (float*)(wsb + ACC_OFF);
        float* cacc = sacc + 32;
        const int j = lane & 15;
        if (j < 8) {                        // 32 lanes, 32 distinct addresses
            const int r   = j & 3;
            const int row = b0 + 4 * kq + r;
            float  val = (j < 4) ? sb[r] : cbv[r];
            float* dst = (j < 4) ? (sacc + row) : (cacc + row);
            __hip_atomic_fetch_add(dst, val, __ATOMIC_RELAXED,
                                   __HIP_MEMORY_SCOPE_AGENT);
        }
        // wave-level drain so all lanes' sum-atomics complete before arrival
        __builtin_amdgcn_s_waitcnt(0);
        unsigned int old = 0u;
        if (lane == 0) {
            unsigned int* cnt = (unsigned int*)(sacc + 64);
            old = __hip_atomic_fetch_add(cnt, 1u, __ATOMIC_ACQ_REL,
                                         __HIP_MEMORY_SCOPE_AGENT);
        }
        const int islast = __shfl((int)(old == NBLK - 1), 0, 64);
        if (islast) {                       // 256th arrival: all sums at L3
            __builtin_amdgcn_fence(__ATOMIC_ACQUIRE, "agent");
            if (lane < BB) {
                float s = __hip_atomic_load(sacc + lane, __ATOMIC_RELAXED,
                                            __HIP_MEMORY_SCOPE_AGENT);
                float c = __hip_atomic_load(cacc + lane, __ATOMIC_RELAXED,
                                            __HIP_MEMORY_SCOPE_AGENT);
                float sm = s * (1.0f / NN), cm = c * (1.0f / NN);
                coh[lane] = sqrtf(sm * sm + cm * cm);
            }
        }
    }
    #undef TAB
}

extern "C" void kernel_launch(void* const* d_in, const int* in_sizes, int n_in,
                              void* d_out, int out_size, void* d_ws, size_t ws_size,
                              hipStream_t stream)
{
    const float* theta0   = (const float*)d_in[0];   // 32*2048
    const float* K        = (const float*)d_in[1];   // 2048*2048
    const float* omega    = (const float*)d_in[2];   // 2048
    const float* K_global = (const float*)d_in[3];   // 1
    const float* mu_gate  = (const float*)d_in[4];   // 1

    float* theta_out = (float*)d_out;                // 65536 floats
    float* coh       = theta_out + BB * NN;          // 32 floats

    // ws needs ~10.6 MB: 128 KB sync region + 10 tables (reverse, 1 MB apart)
    kuramoto_fused<<<dim3(NBLK), dim3(128), 0, stream>>>(
        theta0, K, omega, K_global, mu_gate, theta_out, coh, (char*)d_ws);
}

// Round 3
// 169.350 us; speedup vs baseline: 1.0559x; 1.0559x over previous
//
#include <hip/hip_runtime.h>
#include <hip/hip_bf16.h>
#include <math.h>

#define NN 2048
#define BB 32
#define NT 64                 // total K-dim MFMA iterations: 2048 / 32
#define NBLK 256              // block = (osc_tile 0..127, batch_half 0..1)
#define DT_C 0.1f
#define PI_F 3.14159265358979323846f
#define TWO_PI_F 6.28318530717958647692f
#define MAGIC 0x5EED5EEDu

// ws layout (sync words line-padded):
//   READY @ 256, FLAG b @ 512 + 256*b (b<256)  -> ends at ~66 KB
//   ACC @ 80 KB: sin[32], cos[32] fp32 sums + arrival counter (atomic tail)
//   tables @ 128 KB: 10 per-step packed tables, reverse order, 1 MB apart
#define READY_OFF  256
#define FLAG_OFF   512
#define FLAG_STRIDE 256
#define ACC_OFF    81920
#define TAB_BASE   131072
#define TAB_STRIDE (1u << 20)

typedef __attribute__((ext_vector_type(8))) short short8;
typedef __attribute__((ext_vector_type(4))) float floatx4;

__device__ __forceinline__ unsigned short f2bf(float x) {
    union { float f; unsigned int u; } v; v.f = x;
    unsigned int r = v.u + 0x7FFFu + ((v.u >> 16) & 1u);
    return (unsigned short)(r >> 16);
}

// sc1 write-through store / L2-bypass load (agent-coherent, no cache walks)
__device__ __forceinline__ void st_sc(unsigned int* p, unsigned int v) {
    __hip_atomic_store(p, v, __ATOMIC_RELAXED, __HIP_MEMORY_SCOPE_AGENT);
}
__device__ __forceinline__ unsigned int ld_sc(const unsigned int* p) {
    return __hip_atomic_load((unsigned int*)p, __ATOMIC_RELAXED,
                             __HIP_MEMORY_SCOPE_AGENT);
}

// ROUND-13 sync: distributed gather. Arrivals = round-11 mechanics (one
// line-padded sc1 flag store per block, AFTER table stores drain). But
// instead of block-0 gathering + epoch publish + epoch poll (3 serialized
// L3 hops, and the gather only started after block-0's own update), EVERY
// block's wave 1 gathers all 256 flags itself (4/lane x 64 lanes, 256
// distinct lines -> ~9 loads/us/line, no round-2-style same-line storm).
// Wave 1 is idle during wave 0's update phase, so the gather overlaps
// producer work. Inter-block sync tail = last flag store + one poll RT.
// Round-2 lesson encoded: NEVER aggregate arrivals through a shared
// atomic counter line; parallel stores + parallel gather only.
__device__ __forceinline__ void gather_flags(char* wsb, unsigned int tgt) {
    const unsigned int* f0 = (const unsigned int*)(wsb + FLAG_OFF + (size_t)(4 * (threadIdx.x & 63) + 0) * FLAG_STRIDE);
    const unsigned int* f1 = (const unsigned int*)(wsb + FLAG_OFF + (size_t)(4 * (threadIdx.x & 63) + 1) * FLAG_STRIDE);
    const unsigned int* f2 = (const unsigned int*)(wsb + FLAG_OFF + (size_t)(4 * (threadIdx.x & 63) + 2) * FLAG_STRIDE);
    const unsigned int* f3 = (const unsigned int*)(wsb + FLAG_OFF + (size_t)(4 * (threadIdx.x & 63) + 3) * FLAG_STRIDE);
    for (;;) {
        unsigned int v0 = ld_sc(f0);       // 4 independent loads in flight
        unsigned int v1 = ld_sc(f1);       // before the compare: one RT/iter
        unsigned int v2 = ld_sc(f2);
        unsigned int v3 = ld_sc(f3);
        bool ok = (v0 >= tgt) & (v1 >= tgt) & (v2 >= tgt) & (v3 >= tgt);
        if (__all(ok)) break;
        __builtin_amdgcn_s_sleep(2);
    }
    // no table loads may be scheduled above the poll exit
    __builtin_amdgcn_sched_barrier(0);
}

// unpack packed word pair {(s<<16)|c} x2 -> packed bf16x2 sin and cos
__device__ __forceinline__ void unpack2(unsigned int lo, unsigned int hi,
                                        unsigned int& sp, unsigned int& cp) {
    sp = __builtin_amdgcn_perm(hi, lo, 0x07060302u);  // {s1,s0}
    cp = __builtin_amdgcn_perm(hi, lo, 0x05040100u);  // {c1,c0}
}

// ROUND-13: distributed-gather sync (see above). Compute loop, prologue and
// atomic tail byte-identical to round 11 for clean attribution. red[] is
// step-parity double-buffered -> the two per-step __syncthreads pair wave0's
// read with wave1's write two steps apart (WAR safe).
// Fragment layout (m89/m91-verified): A: lane holds A[m=lane&15][k=(lane>>4)*8+j];
// B mirrored; D: row(batch)=(lane>>4)*4+r, col(osc)=lane&15.
__global__ void __launch_bounds__(128, 1) kuramoto_fused(
    const float* __restrict__ theta0, const float* __restrict__ K,
    const float* __restrict__ omega, const float* __restrict__ K_global,
    const float* __restrict__ mu_gate,
    float* __restrict__ theta_out, float* __restrict__ coh,
    char* __restrict__ wsb)
{
    const int tid  = threadIdx.x;
    const int kh   = tid >> 6;              // K-half this wave covers: 0 or 1
    const int lane = tid & 63;
    const int lrow = lane & 15;
    const int kq   = lane >> 4;             // 0..3
    const int tile = blockIdx.x >> 1;
    const int bh   = blockIdx.x & 1;        // batch half
    const int i0   = tile * 16;
    const int b0   = bh * 16;
    const int i    = i0 + lrow;

    unsigned int* myflag = (unsigned int*)(wsb + FLAG_OFF +
                                           (size_t)blockIdx.x * FLAG_STRIDE);

    // one-time: drop pre-kernel (poison) lines from local caches before any
    // cached table read (belt-and-braces alongside launch acquire)
    __builtin_amdgcn_fence(__ATOMIC_ACQUIRE, "agent");

    // block 0 zeroes the (poisoned) flags + atomic-tail accumulators before
    // the ready handshake (no block may store its flag before zeros land)
    if (blockIdx.x == 0) {
        if (tid < 128) {
            st_sc((unsigned int*)(wsb + FLAG_OFF + (size_t)(2 * tid) * FLAG_STRIDE), 0u);
            st_sc((unsigned int*)(wsb + FLAG_OFF + (size_t)(2 * tid + 1) * FLAG_STRIDE), 0u);
        }
        if (tid < 66)                       // sin[32] cos[32] cnt (+pad)
            st_sc((unsigned int*)(wsb + ACC_OFF) + tid, 0u);
    }

    // per-step table s lives at wsb + TAB_BASE + (10-s)*TAB_STRIDE
    #define TAB(s) ((unsigned int*)(wsb + TAB_BASE + (size_t)(10 - (s)) * TAB_STRIDE))

    const float coef = K_global[0] * (DT_C / (float)NN);    // DT folded in

    // wave 0 owns theta for this block's 16x16 tile; TAB(0) issued first so
    // its stores drain underneath the K staging loads
    float th[4], sb[4], cbv[4], om_dt = 0.f;
    if (kh == 0) {
        om_dt = omega[i] * DT_C;
        #pragma unroll
        for (int r = 0; r < 4; ++r) {
            size_t off = (size_t)(b0 + kq * 4 + r) * NN + i;
            th[r] = theta0[off];
            __sincosf(th[r], &sb[r], &cbv[r]);
            st_sc(&TAB(0)[off], ((unsigned int)f2bf(sb[r]) << 16) | f2bf(cbv[r]));
        }
    }

    // ---- K rows i0..i0+15 -> LDS as pre-scaled bf16 B-fragments ----
    // Batched loads: 16 float4 in flight per thread before converting.
    __shared__ short8 kb[NT * 64];          // 64 KB, kb[t*64 + lane]
    __shared__ floatx4 red[2][2][64];       // step-parity double-buffered P/Q
    const float kscale = mu_gate[0] * 0.5f; // MU_BRANCH_SCALE fold
    for (int g = 0; g < 4; ++g) {
        const int tb = kh * 32 + g * 8;
        float4 buf[16];
        #pragma unroll
        for (int j = 0; j < 8; ++j) {
            const float4* kp = (const float4*)(K + (size_t)i * NN + (tb + j) * 32 + kq * 8);
            buf[2 * j]     = kp[0];
            buf[2 * j + 1] = kp[1];
        }
        #pragma unroll
        for (int j = 0; j < 8; ++j) {
            float4 x = buf[2 * j], y = buf[2 * j + 1];
            short8 f;
            f[0] = (short)f2bf(x.x * kscale); f[1] = (short)f2bf(x.y * kscale);
            f[2] = (short)f2bf(x.z * kscale); f[3] = (short)f2bf(x.w * kscale);
            f[4] = (short)f2bf(y.x * kscale); f[5] = (short)f2bf(y.y * kscale);
            f[6] = (short)f2bf(y.z * kscale); f[7] = (short)f2bf(y.w * kscale);
            kb[(tb + j) * 64 + lane] = f;
        }
    }

    // drain zeros (block 0) + TAB(0) stores + staging; then ready handshake.
    // Guarantees: flag zeros are at L3 before ANY block stores its flag.
    __syncthreads();
    if (tid == 0) {
        unsigned int* ready = (unsigned int*)(wsb + READY_OFF);
        if (blockIdx.x == 0) {
            st_sc(ready, MAGIC);            // zeros at L3 (vmcnt drained)
        } else {
            while (ld_sc(ready) != MAGIC)
                __builtin_amdgcn_s_sleep(8);
        }
        st_sc(myflag, 1u);                  // TAB(0) tile published
    }
    __syncthreads();
    if (kh == 1) gather_flags(wsb, 1u);     // table 0 complete everywhere
    __syncthreads();

    const int c0 = (blockIdx.x * 5) & 15;   // per-block K-loop rotation

    for (int step = 0; step < 10; ++step) {
        const uint4* U = (const uint4*)(TAB(step) + (size_t)(b0 + lrow) * NN);
        unsigned int* tabn = TAB(step + 1);

        floatx4 p0 = {0.f,0.f,0.f,0.f}, p1 = {0.f,0.f,0.f,0.f};
        floatx4 q0 = {0.f,0.f,0.f,0.f}, q1 = {0.f,0.f,0.f,0.f};
        #pragma unroll 4
        for (int c = 0; c < 16; ++c) {      // this wave's K-half: 16 x 2 chunks
            const int t  = kh * 32 + 2 * ((c + c0) & 15);
            const int a0 = 8 * t + 2 * kq;  // uint4 idx: words j0..j0+7
            uint4 ua = U[a0];
            uint4 ub = U[a0 + 1];
            uint4 va = U[a0 + 8];           // chunk t+1
            uint4 vb = U[a0 + 9];
            union { short8 v; unsigned int u[4]; } as0, ac0, as1, ac1;
            unpack2(ua.x, ua.y, as0.u[0], ac0.u[0]);
            unpack2(ua.z, ua.w, as0.u[1], ac0.u[1]);
            unpack2(ub.x, ub.y, as0.u[2], ac0.u[2]);
            unpack2(ub.z, ub.w, as0.u[3], ac0.u[3]);
            unpack2(va.x, va.y, as1.u[0], ac1.u[0]);
            unpack2(va.z, va.w, as1.u[1], ac1.u[1]);
            unpack2(vb.x, vb.y, as1.u[2], ac1.u[2]);
            unpack2(vb.z, vb.w, as1.u[3], ac1.u[3]);
            short8 bk0 = kb[t * 64 + lane];
            short8 bk1 = kb[(t + 1) * 64 + lane];
            p0 = __builtin_amdgcn_mfma_f32_16x16x32_bf16(as0.v, bk0, p0, 0, 0, 0);
            q0 = __builtin_amdgcn_mfma_f32_16x16x32_bf16(ac0.v, bk0, q0, 0, 0, 0);
            p1 = __builtin_amdgcn_mfma_f32_16x16x32_bf16(as1.v, bk1, p1, 0, 0, 0);
            q1 = __builtin_amdgcn_mfma_f32_16x16x32_bf16(ac1.v, bk1, q1, 0, 0, 0);
        }
        floatx4 P = p0 + p1;
        floatx4 Q = q0 + q1;

        // K-split reduction: wave 1 publishes partials...
        if (kh == 1) { red[step & 1][0][lane] = P; red[step & 1][1][lane] = Q; }
        __syncthreads();                    // (A)
        if (kh == 0) {
            // ...wave 0 combines + updates + publishes table(step+1) + flag
            P += red[step & 1][0][lane];
            Q += red[step & 1][1][lane];
            #pragma unroll
            for (int r = 0; r < 4; ++r) {
                float coup = cbv[r] * P[r] - sb[r] * Q[r];
                float tn = th[r] + om_dt + coef * coup;
                if (tn > PI_F)        tn -= TWO_PI_F;   // wrap to (-pi, pi]
                else if (tn <= -PI_F) tn += TWO_PI_F;
                th[r] = tn;
                __sincosf(tn, &sb[r], &cbv[r]);
                size_t off = (size_t)(b0 + kq * 4 + r) * NN + i;
                if (step < 9) {
                    st_sc(&tabn[off], ((unsigned int)f2bf(sb[r]) << 16) | f2bf(cbv[r]));
                } else {
                    theta_out[off] = tn;    // visible at kernel end
                }
            }
            if (step < 9) {
                __builtin_amdgcn_s_waitcnt(0);          // table stores at L3
                if (lane == 0) st_sc(myflag, (unsigned)(step + 2));
            }
        } else if (step < 9) {
            // meanwhile wave 1 (idle in the update phase) gathers the grid:
            // overlaps producer work; sync tail = last flag store + 1 poll RT
            gather_flags(wsb, (unsigned)(step + 2));
        }
        __syncthreads();                    // (B): all tables for step+1 seen
    }

    // ---- atomic coherence tail ----
    // wave 0 holds fp32 sin/cos of the final theta for rows b0+4*kq+r,
    // osc column i0+lrow. Reduce over the 16 osc lanes of each kq group,
    // publish via one 32-lane device-scope f32 atomic, count arrivals.
    if (kh == 0) {
        #pragma unroll
        for (int m = 1; m < 16; m <<= 1) {
            #pragma unroll
            for (int r = 0; r < 4; ++r) {
                sb[r]  += __shfl_xor(sb[r],  m, 64);
                cbv[r] += __shfl_xor(cbv[r], m, 64);
            }
        }
        float* sacc = (float*)(wsb + ACC_OFF);
        float* cacc = sacc + 32;
        const int j = lane & 15;
        if (j < 8) {                        // 32 lanes, 32 distinct addresses
            const int r   = j & 3;
            const int row = b0 + 4 * kq + r;
            float  val = (j < 4) ? sb[r] : cbv[r];
            float* dst = (j < 4) ? (sacc + row) : (cacc + row);
            __hip_atomic_fetch_add(dst, val, __ATOMIC_RELAXED,
                                   __HIP_MEMORY_SCOPE_AGENT);
        }
        // wave-level drain so all lanes' sum-atomics complete before arrival
        __builtin_amdgcn_s_waitcnt(0);
        unsigned int old = 0u;
        if (lane == 0) {
            unsigned int* cnt = (unsigned int*)(sacc + 64);
            old = __hip_atomic_fetch_add(cnt, 1u, __ATOMIC_ACQ_REL,
                                         __HIP_MEMORY_SCOPE_AGENT);
        }
        const int islast = __shfl((int)(old == NBLK - 1), 0, 64);
        if (islast) {                       // 256th arrival: all sums at L3
            __builtin_amdgcn_fence(__ATOMIC_ACQUIRE, "agent");
            if (lane < BB) {
                float s = __hip_atomic_load(sacc + lane, __ATOMIC_RELAXED,
                                            __HIP_MEMORY_SCOPE_AGENT);
                float c = __hip_atomic_load(cacc + lane, __ATOMIC_RELAXED,
                                            __HIP_MEMORY_SCOPE_AGENT);
                float sm = s * (1.0f / NN), cm = c * (1.0f / NN);
                coh[lane] = sqrtf(sm * sm + cm * cm);
            }
        }
    }
    #undef TAB
}

extern "C" void kernel_launch(void* const* d_in, const int* in_sizes, int n_in,
                              void* d_out, int out_size, void* d_ws, size_t ws_size,
                              hipStream_t stream)
{
    const float* theta0   = (const float*)d_in[0];   // 32*2048
    const float* K        = (const float*)d_in[1];   // 2048*2048
    const float* omega    = (const float*)d_in[2];   // 2048
    const float* K_global = (const float*)d_in[3];   // 1
    const float* mu_gate  = (const float*)d_in[4];   // 1

    float* theta_out = (float*)d_out;                // 65536 floats
    float* coh       = theta_out + BB * NN;          // 32 floats

    // ws needs ~10.6 MB: 128 KB sync region + 10 tables (reverse, 1 MB apart)
    kuramoto_fused<<<dim3(NBLK), dim3(128), 0, stream>>>(
        theta0, K, omega, K_global, mu_gate, theta_out, coh, (char*)d_ws);
}

// Round 4
// 155.945 us; speedup vs baseline: 1.1466x; 1.0860x over previous
//
#include <hip/hip_runtime.h>
#include <hip/hip_bf16.h>
#include <math.h>

#define NN 2048
#define BB 32
#define NT 64                 // total K-dim MFMA chunk count: 2048 / 32
#define NBLK 256              // block = (osc_tile 0..127, batch_half 0..1)
#define DT_C 0.1f
#define PI_F 3.14159265358979323846f
#define TWO_PI_F 6.28318530717958647692f
#define MAGIC 0x5EED5EEDu

// ws layout (sync words line-padded):
//   EPOCH @ 0, READY @ 256, FLAG b @ 512 + 256*b (b<256)  -> ends at ~66 KB
//   ACC @ 80 KB: sin[32], cos[32] fp32 sums + arrival counter (atomic tail)
//   tables @ 128 KB: 10 per-step packed tables, reverse order, 1 MB apart
#define EPOCH_OFF  0
#define READY_OFF  256
#define FLAG_OFF   512
#define FLAG_STRIDE 256
#define ACC_OFF    81920
#define TAB_BASE   131072
#define TAB_STRIDE (1u << 20)

typedef __attribute__((ext_vector_type(8))) short short8;
typedef __attribute__((ext_vector_type(4))) float floatx4;

__device__ __forceinline__ unsigned short f2bf(float x) {
    union { float f; unsigned int u; } v; v.f = x;
    unsigned int r = v.u + 0x7FFFu + ((v.u >> 16) & 1u);
    return (unsigned short)(r >> 16);
}

// sc1 write-through store / L2-bypass load (agent-coherent, no cache walks)
__device__ __forceinline__ void st_sc(unsigned int* p, unsigned int v) {
    __hip_atomic_store(p, v, __ATOMIC_RELAXED, __HIP_MEMORY_SCOPE_AGENT);
}
__device__ __forceinline__ unsigned int ld_sc(const unsigned int* p) {
    return __hip_atomic_load((unsigned int*)p, __ATOMIC_RELAXED,
                             __HIP_MEMORY_SCOPE_AGENT);
}

// ROUND-14 sync = round-11 aggregator VERBATIM (best measured: 96.6 us).
// R12 (shared-counter dataflow, +18) and R13 (distributed gather, +8) both
// regressed -> sync topology is not the limiter; this round widens the
// per-CU pipeline instead. Arrivals: one line-padded sc1 store per block.
// Block 0 wave 0 gathers (4 flags/lane, loads issued unconditionally and
// combined bitwise = 1 L3 RT/poll-iter); publishes ONE epoch word; other
// blocks poll epoch with 1 thread + backoff. The opening __syncthreads
// drains each wave's vmcnt -> all 4 waves' table stores are at L3 before
// the flag store.
__device__ __forceinline__ void gridbar(char* wsb, unsigned int tgt) {
    __syncthreads();
    unsigned int* epoch = (unsigned int*)(wsb + EPOCH_OFF);
    if (blockIdx.x == 0) {
        if (threadIdx.x == 0)
            st_sc((unsigned int*)(wsb + FLAG_OFF), tgt);
        if (threadIdx.x < 64) {
            const int lane = threadIdx.x;
            const unsigned int* f0 = (const unsigned int*)(wsb + FLAG_OFF + (size_t)(4 * lane + 0) * FLAG_STRIDE);
            const unsigned int* f1 = (const unsigned int*)(wsb + FLAG_OFF + (size_t)(4 * lane + 1) * FLAG_STRIDE);
            const unsigned int* f2 = (const unsigned int*)(wsb + FLAG_OFF + (size_t)(4 * lane + 2) * FLAG_STRIDE);
            const unsigned int* f3 = (const unsigned int*)(wsb + FLAG_OFF + (size_t)(4 * lane + 3) * FLAG_STRIDE);
            for (;;) {
                unsigned int v0 = ld_sc(f0);   // 4 independent loads in
                unsigned int v1 = ld_sc(f1);   // flight before the compare:
                unsigned int v2 = ld_sc(f2);   // one RT, not four
                unsigned int v3 = ld_sc(f3);
                bool ok = (v0 >= tgt) & (v1 >= tgt) & (v2 >= tgt) & (v3 >= tgt);
                if (__all(ok)) break;
                __builtin_amdgcn_s_sleep(2);
            }
            if (lane == 0) st_sc(epoch, tgt);
        }
    } else {
        if (threadIdx.x == 0) {
            st_sc((unsigned int*)(wsb + FLAG_OFF + (size_t)blockIdx.x * FLAG_STRIDE), tgt);
            while (ld_sc(epoch) < tgt)
                __builtin_amdgcn_s_sleep(4);
        }
    }
    __syncthreads();
}

// unpack packed word pair {(s<<16)|c} x2 -> packed bf16x2 sin and cos
__device__ __forceinline__ void unpack2(unsigned int lo, unsigned int hi,
                                        unsigned int& sp, unsigned int& cp) {
    sp = __builtin_amdgcn_perm(hi, lo, 0x07060302u);  // {s1,s0}
    cp = __builtin_amdgcn_perm(hi, lo, 0x05040100u);  // {c1,c0}
}

// ROUND-14: 4-wave blocks (256 thr). K split 4 ways (8 chunk-iters/wave);
// all 4 SIMDs/CU active (was 2) -> MFMA+unpack wall-clock ~halves; staging
// prologue ~halves. Update split ONE ROW PER WAVE (wave w updates batch row
// b0+kq*4+w): 1 sincos + 1 table store per lane per step, vs 4 serial on a
// single wave. 4-way K-reduction via LDS exchange red[par][wave][P/Q][lane]
// (vector writes, 8 scalar reads of element w). Sync = R11 aggregator.
// Compute expressions, table format, rotation, atomic tail: verified forms.
// Fragment layout (m89/m91-verified): A: lane holds A[m=lane&15][k=(lane>>4)*8+j];
// B mirrored; D: row(batch)=(lane>>4)*4+r, col(osc)=lane&15.
__global__ void __launch_bounds__(256, 1) kuramoto_fused(
    const float* __restrict__ theta0, const float* __restrict__ K,
    const float* __restrict__ omega, const float* __restrict__ K_global,
    const float* __restrict__ mu_gate,
    float* __restrict__ theta_out, float* __restrict__ coh,
    char* __restrict__ wsb)
{
    const int tid   = threadIdx.x;
    const int w     = tid >> 6;             // wave id = K-quarter 0..3
    const int lane  = tid & 63;
    const int lrow  = lane & 15;
    const int kq    = lane >> 4;            // 0..3
    const int tile  = blockIdx.x >> 1;
    const int bh    = blockIdx.x & 1;       // batch half
    const int i0    = tile * 16;
    const int b0    = bh * 16;
    const int i     = i0 + lrow;
    const int qbase = w * 16;               // first chunk of this wave's quarter

    // one-time: drop pre-kernel (poison) lines from local caches before any
    // cached table read (belt-and-braces alongside launch acquire)
    __builtin_amdgcn_fence(__ATOMIC_ACQUIRE, "agent");

    // block 0 zeroes the (poisoned) sync words + atomic-tail accumulators
    // before the ready handshake
    if (blockIdx.x == 0) {
        if (tid < 256)
            st_sc((unsigned int*)(wsb + FLAG_OFF + (size_t)tid * FLAG_STRIDE), 0u);
        if (tid < 66)                       // sin[32] cos[32] cnt (+pad)
            st_sc((unsigned int*)(wsb + ACC_OFF) + tid, 0u);
        if (tid == 0)
            st_sc((unsigned int*)(wsb + EPOCH_OFF), 0u);
    }

    // per-step table s lives at wsb + TAB_BASE + (10-s)*TAB_STRIDE
    #define TAB(s) ((unsigned int*)(wsb + TAB_BASE + (size_t)(10 - (s)) * TAB_STRIDE))

    const float coef = K_global[0] * (DT_C / (float)NN);    // DT folded in

    // wave w owns batch row b0+kq*4+w of this block's 16x16 tile; TAB(0)
    // issued first so its stores drain underneath the K staging loads
    const size_t myoff = (size_t)(b0 + kq * 4 + w) * NN + i;
    const float om_dt = omega[i] * DT_C;
    float th0 = theta0[myoff], sb0, cb0;
    __sincosf(th0, &sb0, &cb0);
    st_sc(&TAB(0)[myoff], ((unsigned int)f2bf(sb0) << 16) | f2bf(cb0));

    // ---- K rows i0..i0+15 -> LDS as pre-scaled bf16 B-fragments ----
    // Each wave stages its own K-quarter (16 chunks); batched float4 loads.
    __shared__ short8 kb[NT * 64];          // 64 KB, kb[t*64 + lane]
    __shared__ floatx4 red[2][4][2][64];    // 16 KB: [par][wave][P/Q][lane]
    const float kscale = mu_gate[0] * 0.5f; // MU_BRANCH_SCALE fold
    for (int g = 0; g < 2; ++g) {
        const int tb = qbase + g * 8;
        float4 buf[16];
        #pragma unroll
        for (int j = 0; j < 8; ++j) {
            const float4* kp = (const float4*)(K + (size_t)i * NN + (tb + j) * 32 + kq * 8);
            buf[2 * j]     = kp[0];
            buf[2 * j + 1] = kp[1];
        }
        #pragma unroll
        for (int j = 0; j < 8; ++j) {
            float4 x = buf[2 * j], y = buf[2 * j + 1];
            short8 f;
            f[0] = (short)f2bf(x.x * kscale); f[1] = (short)f2bf(x.y * kscale);
            f[2] = (short)f2bf(x.z * kscale); f[3] = (short)f2bf(x.w * kscale);
            f[4] = (short)f2bf(y.x * kscale); f[5] = (short)f2bf(y.y * kscale);
            f[6] = (short)f2bf(y.z * kscale); f[7] = (short)f2bf(y.w * kscale);
            kb[(tb + j) * 64 + lane] = f;
        }
    }

    // drain zeros (block 0) + TAB(0) stores + staging; then ready handshake.
    // Guarantees: sync-word zeros are at L3 before ANY block's flag store.
    __syncthreads();
    if (tid == 0) {
        unsigned int* ready = (unsigned int*)(wsb + READY_OFF);
        if (blockIdx.x == 0) {
            st_sc(ready, MAGIC);            // zeros at L3 (vmcnt drained)
        } else {
            while (ld_sc(ready) != MAGIC)   // => zeros visible before our flag
                __builtin_amdgcn_s_sleep(8);
        }
    }
    gridbar(wsb, 1u);                       // table 0 complete everywhere

    const int c0 = (blockIdx.x * 3) & 7;    // per-block K-loop rotation

    for (int step = 0; step < 10; ++step) {
        const int par = step & 1;
        const uint4* U = (const uint4*)(TAB(step) + (size_t)(b0 + lrow) * NN);
        unsigned int* tabn = TAB(step + 1);

        floatx4 p0 = {0.f,0.f,0.f,0.f}, p1 = {0.f,0.f,0.f,0.f};
        floatx4 q0 = {0.f,0.f,0.f,0.f}, q1 = {0.f,0.f,0.f,0.f};
        #pragma unroll 4
        for (int c = 0; c < 8; ++c) {       // this wave's K-quarter: 8 x 2 chunks
            const int t  = qbase + 2 * ((c + c0) & 7);
            const int a0 = 8 * t + 2 * kq;  // uint4 idx: words j0..j0+7
            uint4 ua = U[a0];
            uint4 ub = U[a0 + 1];
            uint4 va = U[a0 + 8];           // chunk t+1
            uint4 vb = U[a0 + 9];
            union { short8 v; unsigned int u[4]; } as0, ac0, as1, ac1;
            unpack2(ua.x, ua.y, as0.u[0], ac0.u[0]);
            unpack2(ua.z, ua.w, as0.u[1], ac0.u[1]);
            unpack2(ub.x, ub.y, as0.u[2], ac0.u[2]);
            unpack2(ub.z, ub.w, as0.u[3], ac0.u[3]);
            unpack2(va.x, va.y, as1.u[0], ac1.u[0]);
            unpack2(va.z, va.w, as1.u[1], ac1.u[1]);
            unpack2(vb.x, vb.y, as1.u[2], ac1.u[2]);
            unpack2(vb.z, vb.w, as1.u[3], ac1.u[3]);
            short8 bk0 = kb[t * 64 + lane];
            short8 bk1 = kb[(t + 1) * 64 + lane];
            p0 = __builtin_amdgcn_mfma_f32_16x16x32_bf16(as0.v, bk0, p0, 0, 0, 0);
            q0 = __builtin_amdgcn_mfma_f32_16x16x32_bf16(ac0.v, bk0, q0, 0, 0, 0);
            p1 = __builtin_amdgcn_mfma_f32_16x16x32_bf16(as1.v, bk1, p1, 0, 0, 0);
            q1 = __builtin_amdgcn_mfma_f32_16x16x32_bf16(ac1.v, bk1, q1, 0, 0, 0);
        }
        floatx4 P = p0 + p1;
        floatx4 Q = q0 + q1;

        // 4-way K-split reduction: every wave publishes full P,Q; after the
        // barrier each wave sums element [w] of all four slots (incl. its
        // own, via LDS -> no dynamic vector extract) and updates its row.
        red[par][w][0][lane] = P;
        red[par][w][1][lane] = Q;
        __syncthreads();
        {
            // flat float idx: par*2048 + v*512 + pq*256 + lane*4 + e
            const float* rf = (const float*)red + par * 2048 + lane * 4;
            float Pw = rf[w]        + rf[w + 512]  + rf[w + 1024] + rf[w + 1536];
            float Qw = rf[w + 256]  + rf[w + 768]  + rf[w + 1280] + rf[w + 1792];
            float coup = cb0 * Pw - sb0 * Qw;
            float tn = th0 + om_dt + coef * coup;
            if (tn > PI_F)        tn -= TWO_PI_F;   // wrap to (-pi, pi]
            else if (tn <= -PI_F) tn += TWO_PI_F;
            th0 = tn;
            __sincosf(tn, &sb0, &cb0);
            if (step < 9) {
                st_sc(&tabn[myoff], ((unsigned int)f2bf(sb0) << 16) | f2bf(cb0));
            } else {
                theta_out[myoff] = tn;      // visible at kernel end
            }
        }
        // gridbar's opening __syncthreads drains each wave's table store
        // (vmcnt(0) before s_barrier) -> flags imply data at L3
        if (step < 9) gridbar(wsb, (unsigned)(step + 2));
    }

    // ---- atomic coherence tail ----
    // Each lane holds fp32 sin/cos of final theta for row b0+kq*4+w, col i.
    // Butterfly all-reduce over the 16 osc lanes of each kq group, then
    // lanes j<2 publish one f32 atomic each (32 adds/block, 64 addresses).
    #pragma unroll
    for (int m = 1; m < 16; m <<= 1) {
        sb0 += __shfl_xor(sb0, m, 64);
        cb0 += __shfl_xor(cb0, m, 64);
    }
    {
        float* sacc = (float*)(wsb + ACC_OFF);
        float* cacc = sacc + 32;
        const int j = lane & 15;
        if (j < 2) {
            const int row = b0 + kq * 4 + w;
            float  val = (j == 0) ? sb0 : cb0;
            float* dst = (j == 0) ? (sacc + row) : (cacc + row);
            __hip_atomic_fetch_add(dst, val, __ATOMIC_RELAXED,
                                   __HIP_MEMORY_SCOPE_AGENT);
        }
        __syncthreads();                    // drains all 4 waves' atomics
        if (w == 0) {
            unsigned int old = 0u;
            if (lane == 0) {
                unsigned int* cnt = (unsigned int*)(sacc + 64);
                old = __hip_atomic_fetch_add(cnt, 1u, __ATOMIC_ACQ_REL,
                                             __HIP_MEMORY_SCOPE_AGENT);
            }
            const int islast = __shfl((int)(old == NBLK - 1), 0, 64);
            if (islast) {                   // 256th arrival: all sums at L3
                __builtin_amdgcn_fence(__ATOMIC_ACQUIRE, "agent");
                if (lane < BB) {
                    float s = __hip_atomic_load(sacc + lane, __ATOMIC_RELAXED,
                                                __HIP_MEMORY_SCOPE_AGENT);
                    float c = __hip_atomic_load(cacc + lane, __ATOMIC_RELAXED,
                                                __HIP_MEMORY_SCOPE_AGENT);
                    float sm = s * (1.0f / NN), cm = c * (1.0f / NN);
                    coh[lane] = sqrtf(sm * sm + cm * cm);
                }
            }
        }
    }
    #undef TAB
}

extern "C" void kernel_launch(void* const* d_in, const int* in_sizes, int n_in,
                              void* d_out, int out_size, void* d_ws, size_t ws_size,
                              hipStream_t stream)
{
    const float* theta0   = (const float*)d_in[0];   // 32*2048
    const float* K        = (const float*)d_in[1];   // 2048*2048
    const float* omega    = (const float*)d_in[2];   // 2048
    const float* K_global = (const float*)d_in[3];   // 1
    const float* mu_gate  = (const float*)d_in[4];   // 1

    float* theta_out = (float*)d_out;                // 65536 floats
    float* coh       = theta_out + BB * NN;          // 32 floats

    // ws needs ~10.6 MB: 128 KB sync region + 10 tables (reverse, 1 MB apart)
    kuramoto_fused<<<dim3(NBLK), dim3(256), 0, stream>>>(
        theta0, K, omega, K_global, mu_gate, theta_out, coh, (char*)d_ws);
}